// Round 1
// baseline (546.590 us; speedup 1.0000x reference)
//
#include <hip/hip_runtime.h>

#define DEV __device__ __forceinline__

typedef unsigned short u16;
typedef unsigned short u16x4 __attribute__((ext_vector_type(4)));
typedef unsigned short u16x8 __attribute__((ext_vector_type(8)));
typedef __bf16 bf16x8 __attribute__((ext_vector_type(8)));
typedef float f32x4 __attribute__((ext_vector_type(4)));
typedef float f32x2 __attribute__((ext_vector_type(2)));

#define BATCH 2
#define SEQ   2048
#define DM    1024
#define DI    2048
#define NS    16
#define RK    64
#define MROWS (BATCH * SEQ)   // 4096
#define NPROJ 96              // RK + 2*NS
#define CHUNK 128
#define NCH   (SEQ / CHUNK)   // 16

DEV u16 f2bf(float x) {
  unsigned u = __builtin_bit_cast(unsigned, x);
  u += 0x7fffu + ((u >> 16) & 1u);
  return (u16)(u >> 16);
}

// ---- MFMA dispatch: robust to either builtin signature (v8i16 or v8bf16) ----
template <typename V>
DEV auto mfma_try(V a, V b, f32x4 c, int)
    -> decltype(__builtin_amdgcn_mfma_f32_16x16x32_bf16(a, b, c, 0, 0, 0)) {
  return __builtin_amdgcn_mfma_f32_16x16x32_bf16(a, b, c, 0, 0, 0);
}
template <typename V>
DEV f32x4 mfma_try(V a, V b, f32x4 c, long) {
  return __builtin_amdgcn_mfma_f32_16x16x32_bf16(
      __builtin_bit_cast(bf16x8, a), __builtin_bit_cast(bf16x8, b), c, 0, 0, 0);
}
DEV f32x4 MFMA(u16x8 a, u16x8 b, f32x4 c) { return mfma_try(a, b, c, 0); }

// ---- elementwise f32 -> bf16 cast (vectorized) ----
__global__ __launch_bounds__(256)
void cast_bf16(const float* __restrict__ in, u16* __restrict__ out, int n4) {
  int i = blockIdx.x * 256 + threadIdx.x;
  if (i < n4) {
    f32x4 v = *(const f32x4*)(in + (size_t)i * 4);
    u16x4 o = { f2bf(v[0]), f2bf(v[1]), f2bf(v[2]), f2bf(v[3]) };
    *(u16x4*)(out + (size_t)i * 4) = o;
  }
}

// ---- transpose + cast: out[n][k] = bf16(in[k][n]), dims % 32 == 0 ----
__global__ __launch_bounds__(256)
void transpose_cast(const float* __restrict__ in, u16* __restrict__ out,
                    int K, int N) {
  __shared__ float tile[32][33];
  const int n0 = blockIdx.x * 32, k0 = blockIdx.y * 32;
  const int c = threadIdx.x & 31, r = threadIdx.x >> 5;
#pragma unroll
  for (int rr = 0; rr < 32; rr += 8)
    tile[rr + r][c] = in[(size_t)(k0 + rr + r) * N + n0 + c];
  __syncthreads();
#pragma unroll
  for (int rr = 0; rr < 32; rr += 8)
    out[(size_t)(n0 + rr + r) * K + k0 + c] = f2bf(tile[c][rr + r]);
}

// ---- bf16 MFMA GEMM: C[M,N] = A[M,K] @ BT[N,K]^T ; 128x128 tile, 4 waves ----
// EPI 0: plain f32 store to O0[M,N]
// EPI 1: col < halfN -> O0[m, col]; else O1[m, col-halfN] = silu(v)
template <int EPI>
__global__ __launch_bounds__(256)
void gemm_bt(const u16* __restrict__ A, const u16* __restrict__ BT,
             int M, int N, int K,
             float* __restrict__ O0, float* __restrict__ O1, int halfN) {
  __shared__ u16 As[128][40];   // 32 + 8 pad -> 16B-aligned rows, low conflicts
  __shared__ u16 Bs[128][40];
  const int t = threadIdx.x;
  const int m0 = blockIdx.y * 128, n0 = blockIdx.x * 128;
  const int lane = t & 63, wid = t >> 6;
  const int wm = (wid >> 1) * 64, wn = (wid & 1) * 64;
  const int lr = lane & 15, lq = lane >> 4;
  const int lk = lq * 4;

  f32x4 acc[4][4];
#pragma unroll
  for (int i = 0; i < 4; ++i)
#pragma unroll
    for (int j = 0; j < 4; ++j) acc[i][j] = f32x4{0.f, 0.f, 0.f, 0.f};

  const int r0 = t >> 2, c0 = (t & 3) * 8;  // rows 0..63
  const int r1 = r0 + 64;                   // rows 64..127

  for (int kt = 0; kt < K; kt += 32) {
    u16x8 a0 = *(const u16x8*)(A + (size_t)(m0 + r0) * K + kt + c0);
    u16x8 a1 = *(const u16x8*)(A + (size_t)(m0 + r1) * K + kt + c0);
    u16x8 b0 = *(const u16x8*)(BT + (size_t)(n0 + r0) * K + kt + c0);
    u16x8 b1 = *(const u16x8*)(BT + (size_t)(n0 + r1) * K + kt + c0);
    __syncthreads();
    *(u16x8*)&As[r0][c0] = a0;
    *(u16x8*)&As[r1][c0] = a1;
    *(u16x8*)&Bs[r0][c0] = b0;
    *(u16x8*)&Bs[r1][c0] = b1;
    __syncthreads();

    u16x8 af[4], bfr[4];
#pragma unroll
    for (int i = 0; i < 4; ++i) {
      u16x4 lo = *(const u16x4*)&As[wm + i * 16 + lr][lk];
      u16x4 hi = *(const u16x4*)&As[wm + i * 16 + lr][lk + 16];
      af[i] = __builtin_shufflevector(lo, hi, 0, 1, 2, 3, 4, 5, 6, 7);
      u16x4 blo = *(const u16x4*)&Bs[wn + i * 16 + lr][lk];
      u16x4 bhi = *(const u16x4*)&Bs[wn + i * 16 + lr][lk + 16];
      bfr[i] = __builtin_shufflevector(blo, bhi, 0, 1, 2, 3, 4, 5, 6, 7);
    }
#pragma unroll
    for (int i = 0; i < 4; ++i)
#pragma unroll
      for (int j = 0; j < 4; ++j)
        acc[i][j] = MFMA(af[i], bfr[j], acc[i][j]);
  }

#pragma unroll
  for (int i = 0; i < 4; ++i) {
    const int row0 = m0 + wm + i * 16 + lq * 4;
#pragma unroll
    for (int j = 0; j < 4; ++j) {
      const int col = n0 + wn + j * 16 + lr;
#pragma unroll
      for (int r = 0; r < 4; ++r) {
        float v = acc[i][j][r];
        const int row = row0 + r;
        if (EPI == 0) {
          O0[(size_t)row * N + col] = v;
        } else {
          if (col < halfN) {
            O0[(size_t)row * halfN + col] = v;
          } else {
            O1[(size_t)row * halfN + (col - halfN)] = v / (1.f + __expf(-v));
          }
        }
      }
    }
  }
}

// ---- depthwise causal conv (k=4) + SiLU ----
__global__ __launch_bounds__(256)
void conv_silu(const float* __restrict__ xin, const float* __restrict__ w,
               const float* __restrict__ cb, float* __restrict__ xc) {
  int idx = blockIdx.x * 256 + threadIdx.x;  // (b, t, d4)
  int d4 = idx & 511;
  int tt = (idx >> 9) & 2047;
  int b = idx >> 20;
  const f32x4* w4 = (const f32x4*)w;
  f32x4 wt[4];
#pragma unroll
  for (int j = 0; j < 4; ++j) wt[j] = w4[d4 * 4 + j];  // taps for d = 4*d4+j
  f32x4 acc = *(const f32x4*)(cb + d4 * 4);
#pragma unroll
  for (int k = 0; k < 4; ++k) {
    int ts = tt - 3 + k;
    if (ts >= 0) {
      f32x4 xv = *(const f32x4*)(xin + ((size_t)(b * 2048 + ts) * 512 + d4) * 4);
      acc[0] += xv[0] * wt[0][k];
      acc[1] += xv[1] * wt[1][k];
      acc[2] += xv[2] * wt[2][k];
      acc[3] += xv[3] * wt[3][k];
    }
  }
  f32x4 o;
#pragma unroll
  for (int j = 0; j < 4; ++j) o[j] = acc[j] / (1.f + __expf(-acc[j]));
  *(f32x4*)(xc + ((size_t)(b * 2048 + tt) * 512 + d4) * 4) = o;
}

// ---- proj = xc @ W_xproj : (4096,2048) @ (2048,96), fp32 ----
__global__ __launch_bounds__(256)
void proj_kernel(const float* __restrict__ xc, const float* __restrict__ Wxp,
                 float* __restrict__ proj) {
  __shared__ float xs[16][68];
  __shared__ float ws[64][96];
  const int m0 = blockIdx.x * 16;
  const int t = threadIdx.x;
  const int ml = t >> 4, ng = t & 15, nb = ng * 6;
  float acc[6] = {0.f, 0.f, 0.f, 0.f, 0.f, 0.f};
  for (int kt = 0; kt < DI; kt += 64) {
    __syncthreads();
    {
      int r = t >> 4, c4 = (t & 15) * 4;
      *(f32x4*)&xs[r][c4] = *(const f32x4*)(xc + (size_t)(m0 + r) * DI + kt + c4);
    }
#pragma unroll
    for (int q = 0; q < 6; ++q) {
      int u = t + q * 256;
      int r = u / 24, c4 = (u % 24) * 4;
      *(f32x4*)&ws[r][c4] = *(const f32x4*)(Wxp + (size_t)(kt + r) * NPROJ + c4);
    }
    __syncthreads();
#pragma unroll 4
    for (int kk = 0; kk < 64; ++kk) {
      float a = xs[ml][kk];
      f32x2 w01 = *(const f32x2*)&ws[kk][nb];
      f32x2 w23 = *(const f32x2*)&ws[kk][nb + 2];
      f32x2 w45 = *(const f32x2*)&ws[kk][nb + 4];
      acc[0] += a * w01[0]; acc[1] += a * w01[1];
      acc[2] += a * w23[0]; acc[3] += a * w23[1];
      acc[4] += a * w45[0]; acc[5] += a * w45[1];
    }
  }
#pragma unroll
  for (int j = 0; j < 6; ++j)
    proj[(size_t)(m0 + ml) * NPROJ + nb + j] = acc[j];
}

// ---- dt = softplus(proj[:, :64] @ W_dt + b_dt) : K=64 ----
__global__ __launch_bounds__(256)
void dt_kernel(const float* __restrict__ proj, const float* __restrict__ Wdt,
               const float* __restrict__ bdt, float* __restrict__ dtout) {
  __shared__ float ps[16][64];
  const int m0 = blockIdx.y * 16, nb = blockIdx.x * 256;
  const int t = threadIdx.x;
  {
    int r = t >> 4, c4 = (t & 15) * 4;
    *(f32x4*)&ps[r][c4] = *(const f32x4*)(proj + (size_t)(m0 + r) * NPROJ + c4);
  }
  __syncthreads();
  const int n = nb + t;
  float acc[16];
#pragma unroll
  for (int m = 0; m < 16; ++m) acc[m] = 0.f;
  for (int kk = 0; kk < RK; ++kk) {
    float wv = Wdt[(size_t)kk * DI + n];
#pragma unroll
    for (int m = 0; m < 16; ++m) acc[m] += ps[m][kk] * wv;
  }
  float bv = bdt[n];
#pragma unroll
  for (int m = 0; m < 16; ++m) {
    float v = acc[m] + bv;
    v = (v > 20.f) ? v : log1pf(__expf(v));
    dtout[(size_t)(m0 + m) * DI + n] = v;
  }
}

// ---- scan pass 1: per-chunk P = prod(dA), S = local final h ----
__global__ __launch_bounds__(256)
void scan1(const float* __restrict__ dt, const float* __restrict__ xc,
           const float* __restrict__ proj, const float* __restrict__ A_log,
           float* __restrict__ P, float* __restrict__ S) {
  const int c = blockIdx.x, dblk = blockIdx.y, b = blockIdx.z;
  const int dl = threadIdx.x & 15, n = threadIdx.x >> 4;
  const int d = dblk * 16 + dl;
  const float a = -__expf(A_log[d * NS + n]);
  float Pv = 1.f, Sv = 0.f;
  const size_t mbase = (size_t)b * SEQ + c * CHUNK;
  const float* dtp = dt + mbase * DI + d;
  const float* xcp = xc + mbase * DI + d;
  const float* prp = proj + mbase * NPROJ + RK + n;
  for (int tt = 0; tt < CHUNK; ++tt) {
    float dtv = dtp[(size_t)tt * DI];
    float xv  = xcp[(size_t)tt * DI];
    float Bv  = prp[(size_t)tt * NPROJ];
    float dA = __expf(dtv * a);
    Pv *= dA;
    Sv = Sv * dA + dtv * xv * Bv;
  }
  size_t off = ((size_t)(b * NCH + c) * NS + n) * DI + d;
  P[off] = Pv;
  S[off] = Sv;
}

// ---- scan pass 2: exclusive scan across chunks ----
__global__ __launch_bounds__(256)
void scan2(const float* __restrict__ P, const float* __restrict__ S,
           float* __restrict__ h0) {
  int idx = blockIdx.x * 256 + threadIdx.x;  // [0, BATCH*NS*DI)
  int b = idx >> 15, rem = idx & 32767;
  float h = 0.f;
#pragma unroll
  for (int c = 0; c < NCH; ++c) {
    size_t off = ((size_t)(b * NCH + c) << 15) + rem;
    h0[off] = h;
    h = P[off] * h + S[off];
  }
}

// ---- scan pass 3: recompute with h0, reduce over n, fuse skip+gate+bf16 ----
__global__ __launch_bounds__(256)
void scan3(const float* __restrict__ dt, const float* __restrict__ xc,
           const float* __restrict__ proj, const float* __restrict__ A_log,
           const float* __restrict__ Dskip, const float* __restrict__ h0,
           const float* __restrict__ sz, u16* __restrict__ yg) {
  const int c = blockIdx.x, dblk = blockIdx.y, b = blockIdx.z;
  const int n = threadIdx.x & 15, dl = threadIdx.x >> 4;
  const int d = dblk * 16 + dl;
  const float a = -__expf(A_log[d * NS + n]);
  const float dsk = Dskip[d];
  float h = h0[((size_t)(b * NCH + c) * NS + n) * DI + d];
  const size_t mbase = (size_t)b * SEQ + c * CHUNK;
  for (int tt = 0; tt < CHUNK; ++tt) {
    const size_t m = mbase + tt;
    float dtv = dt[m * DI + d];
    float xv  = xc[m * DI + d];
    float Bv  = proj[m * NPROJ + RK + n];
    float Cv  = proj[m * NPROJ + RK + NS + n];
    float dA = __expf(dtv * a);
    h = h * dA + dtv * xv * Bv;
    float p = h * Cv;
    p += __shfl_xor(p, 1, 16);
    p += __shfl_xor(p, 2, 16);
    p += __shfl_xor(p, 4, 16);
    p += __shfl_xor(p, 8, 16);
    if (n == 0) {
      float y = (p + xv * dsk) * sz[m * DI + d];
      yg[m * DI + d] = f2bf(y);
    }
  }
}

extern "C" void kernel_launch(void* const* d_in, const int* in_sizes, int n_in,
                              void* d_out, int out_size, void* d_ws, size_t ws_size,
                              hipStream_t stream) {
  const float* x      = (const float*)d_in[0];
  const float* W_in   = (const float*)d_in[1];
  const float* conv_w = (const float*)d_in[2];
  const float* conv_b = (const float*)d_in[3];
  const float* W_xp   = (const float*)d_in[4];
  const float* W_dt   = (const float*)d_in[5];
  const float* b_dt   = (const float*)d_in[6];
  const float* A_log  = (const float*)d_in[7];
  const float* Dskip  = (const float*)d_in[8];
  const float* W_out  = (const float*)d_in[9];
  float* out = (float*)d_out;

  char* w = (char*)d_ws;
  u16* xbf    = (u16*)w;   w += (size_t)MROWS * DM * 2;            // 8 MB
  u16* WinT   = (u16*)w;   w += (size_t)(2 * DI) * DM * 2;         // 8 MB
  u16* WoutT  = (u16*)w;   w += (size_t)DM * DI * 2;               // 4 MB
  float* xin  = (float*)w; w += (size_t)MROWS * DI * 4;            // 32 MB
  float* sz   = (float*)w; w += (size_t)MROWS * DI * 4;            // 32 MB
  float* xc   = (float*)w; w += (size_t)MROWS * DI * 4;            // 32 MB
  float* proj = (float*)w; w += (size_t)MROWS * NPROJ * 4;         // 1.5 MB
  float* dtb  = (float*)w; w += (size_t)MROWS * DI * 4;            // 32 MB
  float* Pb   = (float*)w; w += (size_t)BATCH * NCH * NS * DI * 4; // 4 MB
  float* Sb   = (float*)w; w += (size_t)BATCH * NCH * NS * DI * 4; // 4 MB
  float* h0b  = (float*)w; w += (size_t)BATCH * NCH * NS * DI * 4; // 4 MB
  u16* yg     = (u16*)w;   w += (size_t)MROWS * DI * 2;            // 16 MB

  cast_bf16<<<(MROWS * DM / 4 + 255) / 256, 256, 0, stream>>>(x, xbf, MROWS * DM / 4);
  transpose_cast<<<dim3((2 * DI) / 32, DM / 32), 256, 0, stream>>>(W_in, WinT, DM, 2 * DI);
  transpose_cast<<<dim3(DM / 32, DI / 32), 256, 0, stream>>>(W_out, WoutT, DI, DM);

  gemm_bt<1><<<dim3((2 * DI) / 128, MROWS / 128), 256, 0, stream>>>(
      xbf, WinT, MROWS, 2 * DI, DM, xin, sz, DI);

  conv_silu<<<(MROWS * DI / 4) / 256, 256, 0, stream>>>(xin, conv_w, conv_b, xc);

  proj_kernel<<<MROWS / 16, 256, 0, stream>>>(xc, W_xp, proj);

  dt_kernel<<<dim3(DI / 256, MROWS / 16), 256, 0, stream>>>(proj, W_dt, b_dt, dtb);

  scan1<<<dim3(NCH, DI / 16, BATCH), 256, 0, stream>>>(dtb, xc, proj, A_log, Pb, Sb);
  scan2<<<(BATCH * NS * DI) / 256, 256, 0, stream>>>(Pb, Sb, h0b);
  scan3<<<dim3(NCH, DI / 16, BATCH), 256, 0, stream>>>(dtb, xc, proj, A_log, Dskip, h0b, sz, yg);

  gemm_bt<0><<<dim3(DM / 128, MROWS / 128), 256, 0, stream>>>(
      yg, WoutT, MROWS, DM, DI, out, nullptr, 0);
}

// Round 2
// 495.872 us; speedup vs baseline: 1.1023x; 1.1023x over previous
//
#include <hip/hip_runtime.h>

#define DEV __device__ __forceinline__

typedef unsigned short u16;
typedef unsigned short u16x4 __attribute__((ext_vector_type(4)));
typedef unsigned short u16x8 __attribute__((ext_vector_type(8)));
typedef __bf16 bf16x8 __attribute__((ext_vector_type(8)));
typedef float f32x4 __attribute__((ext_vector_type(4)));
typedef float f32x2 __attribute__((ext_vector_type(2)));

#define BATCH 2
#define SEQ   2048
#define DM    1024
#define DI    2048
#define NS    16
#define RK    64
#define MROWS (BATCH * SEQ)   // 4096
#define NPROJ 96              // RK + 2*NS
#define CHUNK 64
#define NCH   (SEQ / CHUNK)   // 32

DEV u16 f2bf(float x) {
  unsigned u = __builtin_bit_cast(unsigned, x);
  u += 0x7fffu + ((u >> 16) & 1u);
  return (u16)(u >> 16);
}

// ---- MFMA dispatch: robust to either builtin signature (v8i16 or v8bf16) ----
template <typename V>
DEV auto mfma_try(V a, V b, f32x4 c, int)
    -> decltype(__builtin_amdgcn_mfma_f32_16x16x32_bf16(a, b, c, 0, 0, 0)) {
  return __builtin_amdgcn_mfma_f32_16x16x32_bf16(a, b, c, 0, 0, 0);
}
template <typename V>
DEV f32x4 mfma_try(V a, V b, f32x4 c, long) {
  return __builtin_amdgcn_mfma_f32_16x16x32_bf16(
      __builtin_bit_cast(bf16x8, a), __builtin_bit_cast(bf16x8, b), c, 0, 0, 0);
}
DEV f32x4 MFMA(u16x8 a, u16x8 b, f32x4 c) { return mfma_try(a, b, c, 0); }

// ---- async global->LDS, 16B per lane (dest = uniform base + lane*16) ----
DEV void gload16(const void* g, void* l) {
  __builtin_amdgcn_global_load_lds(
      (const __attribute__((address_space(1))) unsigned int*)g,
      (__attribute__((address_space(3))) unsigned int*)l, 16, 0, 0);
}

// ---- elementwise f32 -> bf16 cast (vectorized) ----
__global__ __launch_bounds__(256)
void cast_bf16(const float* __restrict__ in, u16* __restrict__ out, int n4) {
  int i = blockIdx.x * 256 + threadIdx.x;
  if (i < n4) {
    f32x4 v = *(const f32x4*)(in + (size_t)i * 4);
    u16x4 o = { f2bf(v[0]), f2bf(v[1]), f2bf(v[2]), f2bf(v[3]) };
    *(u16x4*)(out + (size_t)i * 4) = o;
  }
}

// ---- transpose + cast: out[n][k] = bf16(in[k][n]), dims % 32 == 0 ----
__global__ __launch_bounds__(256)
void transpose_cast(const float* __restrict__ in, u16* __restrict__ out,
                    int K, int N) {
  __shared__ float tile[32][33];
  const int n0 = blockIdx.x * 32, k0 = blockIdx.y * 32;
  const int c = threadIdx.x & 31, r = threadIdx.x >> 5;
#pragma unroll
  for (int rr = 0; rr < 32; rr += 8)
    tile[rr + r][c] = in[(size_t)(k0 + rr + r) * N + n0 + c];
  __syncthreads();
#pragma unroll
  for (int rr = 0; rr < 32; rr += 8)
    out[(size_t)(n0 + rr + r) * K + k0 + c] = f2bf(tile[c][rr + r]);
}

// ---- bf16 MFMA GEMM (m97 structure): C[M,N] = A[M,K] @ BT[N,K]^T ----
// 128x128 tile, BK=32, 4 waves, linear LDS + global_load_lds width-16.
// EPI 0: plain f32 store to O0[M,N]
// EPI 1: col < halfN -> O0[m, col]; else O1[m, col-halfN] = silu(v)
template <int EPI>
__global__ __launch_bounds__(256)
void gemm_bt(const u16* __restrict__ A, const u16* __restrict__ BT,
             int M, int N, int K,
             float* __restrict__ O0, float* __restrict__ O1, int halfN) {
  __shared__ u16 As[128 * 32];
  __shared__ u16 Bs[128 * 32];
  const int t = threadIdx.x;
  const int m0 = blockIdx.y * 128, n0 = blockIdx.x * 128;
  const int lane = t & 63, wid = t >> 6;
  const int wm = (wid >> 1) * 64, wn = (wid & 1) * 64;
  const int lr = lane & 15, lq = lane >> 4;
  const int lk = lq * 4;

  f32x4 acc[4][4];
#pragma unroll
  for (int i = 0; i < 4; ++i)
#pragma unroll
    for (int j = 0; j < 4; ++j) acc[i][j] = f32x4{0.f, 0.f, 0.f, 0.f};

  // staging geometry: seg = wid*2+q covers LDS bytes [seg*1024, +1024)
  // lane l -> row = seg*16 + l/4, col(u16) = (l&3)*8
  const int colu = (lane & 3) * 8;

  for (int kt = 0; kt < K; kt += 32) {
#pragma unroll
    for (int q = 0; q < 2; ++q) {
      const int seg = wid * 2 + q;
      const int row = seg * 16 + (lane >> 2);
      gload16(A + (size_t)(m0 + row) * K + kt + colu, (char*)As + seg * 1024);
      gload16(BT + (size_t)(n0 + row) * K + kt + colu, (char*)Bs + seg * 1024);
    }
    __syncthreads();  // drains vmcnt(0): staged data visible

    u16x8 af[4], bfr[4];
#pragma unroll
    for (int i = 0; i < 4; ++i) {
      const int ra = (wm + i * 16 + lr) * 32;
      u16x4 lo = *(const u16x4*)&As[ra + lk];
      u16x4 hi = *(const u16x4*)&As[ra + lk + 16];
      af[i] = __builtin_shufflevector(lo, hi, 0, 1, 2, 3, 4, 5, 6, 7);
      const int rb = (wn + i * 16 + lr) * 32;
      u16x4 blo = *(const u16x4*)&Bs[rb + lk];
      u16x4 bhi = *(const u16x4*)&Bs[rb + lk + 16];
      bfr[i] = __builtin_shufflevector(blo, bhi, 0, 1, 2, 3, 4, 5, 6, 7);
    }
#pragma unroll
    for (int i = 0; i < 4; ++i)
#pragma unroll
      for (int j = 0; j < 4; ++j)
        acc[i][j] = MFMA(af[i], bfr[j], acc[i][j]);
    __syncthreads();  // all reads done before next stage overwrites
  }

#pragma unroll
  for (int i = 0; i < 4; ++i) {
    const int row0 = m0 + wm + i * 16 + lq * 4;
#pragma unroll
    for (int j = 0; j < 4; ++j) {
      const int col = n0 + wn + j * 16 + lr;
#pragma unroll
      for (int r = 0; r < 4; ++r) {
        float v = acc[i][j][r];
        const int row = row0 + r;
        if (EPI == 0) {
          O0[(size_t)row * N + col] = v;
        } else {
          if (col < halfN) {
            O0[(size_t)row * halfN + col] = v;
          } else {
            O1[(size_t)row * halfN + (col - halfN)] = v / (1.f + __expf(-v));
          }
        }
      }
    }
  }
}

// ---- depthwise causal conv (k=4) + SiLU ----
__global__ __launch_bounds__(256)
void conv_silu(const float* __restrict__ xin, const float* __restrict__ w,
               const float* __restrict__ cb, float* __restrict__ xc) {
  int idx = blockIdx.x * 256 + threadIdx.x;  // (b, t, d4)
  int d4 = idx & 511;
  int tt = (idx >> 9) & 2047;
  int b = idx >> 20;
  const f32x4* w4 = (const f32x4*)w;
  f32x4 wt[4];
#pragma unroll
  for (int j = 0; j < 4; ++j) wt[j] = w4[d4 * 4 + j];  // taps for d = 4*d4+j
  f32x4 acc = *(const f32x4*)(cb + d4 * 4);
#pragma unroll
  for (int k = 0; k < 4; ++k) {
    int ts = tt - 3 + k;
    if (ts >= 0) {
      f32x4 xv = *(const f32x4*)(xin + ((size_t)(b * 2048 + ts) * 512 + d4) * 4);
      acc[0] += xv[0] * wt[0][k];
      acc[1] += xv[1] * wt[1][k];
      acc[2] += xv[2] * wt[2][k];
      acc[3] += xv[3] * wt[3][k];
    }
  }
  f32x4 o;
#pragma unroll
  for (int j = 0; j < 4; ++j) o[j] = acc[j] / (1.f + __expf(-acc[j]));
  *(f32x4*)(xc + ((size_t)(b * 2048 + tt) * 512 + d4) * 4) = o;
}

// ---- proj = xc @ W_xproj : (4096,2048) @ (2048,96), fp32 ----
__global__ __launch_bounds__(256)
void proj_kernel(const float* __restrict__ xc, const float* __restrict__ Wxp,
                 float* __restrict__ proj) {
  __shared__ float xs[16][68];
  __shared__ float ws[64][96];
  const int m0 = blockIdx.x * 16;
  const int t = threadIdx.x;
  const int ml = t >> 4, ng = t & 15, nb = ng * 6;
  float acc[6] = {0.f, 0.f, 0.f, 0.f, 0.f, 0.f};
  for (int kt = 0; kt < DI; kt += 64) {
    __syncthreads();
    {
      int r = t >> 4, c4 = (t & 15) * 4;
      *(f32x4*)&xs[r][c4] = *(const f32x4*)(xc + (size_t)(m0 + r) * DI + kt + c4);
    }
#pragma unroll
    for (int q = 0; q < 6; ++q) {
      int u = t + q * 256;
      int r = u / 24, c4 = (u % 24) * 4;
      *(f32x4*)&ws[r][c4] = *(const f32x4*)(Wxp + (size_t)(kt + r) * NPROJ + c4);
    }
    __syncthreads();
#pragma unroll 4
    for (int kk = 0; kk < 64; ++kk) {
      float a = xs[ml][kk];
      f32x2 w01 = *(const f32x2*)&ws[kk][nb];
      f32x2 w23 = *(const f32x2*)&ws[kk][nb + 2];
      f32x2 w45 = *(const f32x2*)&ws[kk][nb + 4];
      acc[0] += a * w01[0]; acc[1] += a * w01[1];
      acc[2] += a * w23[0]; acc[3] += a * w23[1];
      acc[4] += a * w45[0]; acc[5] += a * w45[1];
    }
  }
#pragma unroll
  for (int j = 0; j < 6; ++j)
    proj[(size_t)(m0 + ml) * NPROJ + nb + j] = acc[j];
}

// ---- dt = softplus(proj[:, :64] @ W_dt + b_dt) : K=64 ----
__global__ __launch_bounds__(256)
void dt_kernel(const float* __restrict__ proj, const float* __restrict__ Wdt,
               const float* __restrict__ bdt, float* __restrict__ dtout) {
  __shared__ float ps[16][64];
  const int m0 = blockIdx.y * 16, nb = blockIdx.x * 256;
  const int t = threadIdx.x;
  {
    int r = t >> 4, c4 = (t & 15) * 4;
    *(f32x4*)&ps[r][c4] = *(const f32x4*)(proj + (size_t)(m0 + r) * NPROJ + c4);
  }
  __syncthreads();
  const int n = nb + t;
  float acc[16];
#pragma unroll
  for (int m = 0; m < 16; ++m) acc[m] = 0.f;
  for (int kk = 0; kk < RK; ++kk) {
    float wv = Wdt[(size_t)kk * DI + n];
#pragma unroll
    for (int m = 0; m < 16; ++m) acc[m] += ps[m][kk] * wv;
  }
  float bv = bdt[n];
#pragma unroll
  for (int m = 0; m < 16; ++m) {
    float v = acc[m] + bv;
    v = (v > 20.f) ? v : log1pf(__expf(v));
    dtout[(size_t)(m0 + m) * DI + n] = v;
  }
}

// ---- scan pass 1: thread owns d, 16 states in regs. P via exp(a*sum(dt)). ----
__global__ __launch_bounds__(256)
void scan1(const float* __restrict__ dt, const float* __restrict__ xc,
           const float* __restrict__ proj, const float* __restrict__ A_log,
           float* __restrict__ P, float* __restrict__ S) {
  __shared__ float Bs[CHUNK][16];
  const int c = blockIdx.x, dblk = blockIdx.y, b = blockIdx.z;
  const int d = (dblk << 8) + threadIdx.x;
  const size_t mbase = (size_t)b * SEQ + (size_t)c * CHUNK;
  {
    int tt = threadIdx.x >> 2, q = (threadIdx.x & 3) * 4;
    *(f32x4*)&Bs[tt][q] = *(const f32x4*)(proj + (mbase + tt) * NPROJ + RK + q);
  }
  __syncthreads();

  float a[16], h[16];
#pragma unroll
  for (int i = 0; i < 4; ++i) {
    f32x4 v = *(const f32x4*)(A_log + (size_t)d * NS + i * 4);
    a[4 * i + 0] = -__expf(v[0]); a[4 * i + 1] = -__expf(v[1]);
    a[4 * i + 2] = -__expf(v[2]); a[4 * i + 3] = -__expf(v[3]);
  }
#pragma unroll
  for (int n = 0; n < 16; ++n) h[n] = 0.f;

  float sumdt = 0.f;
  const float* dtp = dt + mbase * DI + d;
  const float* xcp = xc + mbase * DI + d;
  for (int tt = 0; tt < CHUNK; ++tt) {
    float dtv = dtp[(size_t)tt * DI];
    float xv  = xcp[(size_t)tt * DI];
    sumdt += dtv;
    float dx = dtv * xv;
    float Bv[16];
    *(f32x4*)&Bv[0]  = *(const f32x4*)&Bs[tt][0];
    *(f32x4*)&Bv[4]  = *(const f32x4*)&Bs[tt][4];
    *(f32x4*)&Bv[8]  = *(const f32x4*)&Bs[tt][8];
    *(f32x4*)&Bv[12] = *(const f32x4*)&Bs[tt][12];
#pragma unroll
    for (int n = 0; n < 16; ++n)
      h[n] = h[n] * __expf(dtv * a[n]) + dx * Bv[n];
  }

  const size_t off = ((size_t)(b * NCH + c) * NS) * DI + d;
#pragma unroll
  for (int n = 0; n < 16; ++n) {
    P[off + (size_t)n * DI] = __expf(a[n] * sumdt);
    S[off + (size_t)n * DI] = h[n];
  }
}

// ---- scan pass 2: exclusive scan across chunks ----
__global__ __launch_bounds__(256)
void scan2(const float* __restrict__ P, const float* __restrict__ S,
           float* __restrict__ h0) {
  int idx = blockIdx.x * 256 + threadIdx.x;  // [0, BATCH*NS*DI)
  int b = idx >> 15, rem = idx & 32767;
  float h = 0.f;
#pragma unroll
  for (int c = 0; c < NCH; ++c) {
    size_t off = ((size_t)(b * NCH + c) << 15) + rem;
    h0[off] = h;
    h = P[off] * h + S[off];
  }
}

// ---- scan pass 3: recompute with h0; in-register n-reduction; gate+bf16 ----
__global__ __launch_bounds__(256)
void scan3(const float* __restrict__ dt, const float* __restrict__ xc,
           const float* __restrict__ proj, const float* __restrict__ A_log,
           const float* __restrict__ Dskip, const float* __restrict__ h0,
           const float* __restrict__ sz, u16* __restrict__ yg) {
  __shared__ float Bs[CHUNK][16];
  __shared__ float Cs[CHUNK][16];
  const int c = blockIdx.x, dblk = blockIdx.y, b = blockIdx.z;
  const int d = (dblk << 8) + threadIdx.x;
  const size_t mbase = (size_t)b * SEQ + (size_t)c * CHUNK;
  {
    int tt = threadIdx.x >> 2, q = (threadIdx.x & 3) * 4;
    const float* pr = proj + (mbase + tt) * NPROJ + RK;
    *(f32x4*)&Bs[tt][q] = *(const f32x4*)(pr + q);
    *(f32x4*)&Cs[tt][q] = *(const f32x4*)(pr + NS + q);
  }
  __syncthreads();

  float a[16], h[16];
#pragma unroll
  for (int i = 0; i < 4; ++i) {
    f32x4 v = *(const f32x4*)(A_log + (size_t)d * NS + i * 4);
    a[4 * i + 0] = -__expf(v[0]); a[4 * i + 1] = -__expf(v[1]);
    a[4 * i + 2] = -__expf(v[2]); a[4 * i + 3] = -__expf(v[3]);
  }
  const size_t hoff = ((size_t)(b * NCH + c) * NS) * DI + d;
#pragma unroll
  for (int n = 0; n < 16; ++n) h[n] = h0[hoff + (size_t)n * DI];

  const float dsk = Dskip[d];
  const float* dtp = dt + mbase * DI + d;
  const float* xcp = xc + mbase * DI + d;
  const float* szp = sz + mbase * DI + d;
  u16* ygp = yg + mbase * DI + d;

  for (int tt = 0; tt < CHUNK; ++tt) {
    float dtv = dtp[(size_t)tt * DI];
    float xv  = xcp[(size_t)tt * DI];
    float szv = szp[(size_t)tt * DI];
    float dx = dtv * xv;
    float Bv[16], Cv[16];
    *(f32x4*)&Bv[0]  = *(const f32x4*)&Bs[tt][0];
    *(f32x4*)&Bv[4]  = *(const f32x4*)&Bs[tt][4];
    *(f32x4*)&Bv[8]  = *(const f32x4*)&Bs[tt][8];
    *(f32x4*)&Bv[12] = *(const f32x4*)&Bs[tt][12];
    *(f32x4*)&Cv[0]  = *(const f32x4*)&Cs[tt][0];
    *(f32x4*)&Cv[4]  = *(const f32x4*)&Cs[tt][4];
    *(f32x4*)&Cv[8]  = *(const f32x4*)&Cs[tt][8];
    *(f32x4*)&Cv[12] = *(const f32x4*)&Cs[tt][12];
    float y0 = 0.f, y1 = 0.f, y2 = 0.f, y3 = 0.f;
#pragma unroll
    for (int n = 0; n < 16; ++n) {
      h[n] = h[n] * __expf(dtv * a[n]) + dx * Bv[n];
      float yv = h[n] * Cv[n];
      if ((n & 3) == 0) y0 += yv;
      else if ((n & 3) == 1) y1 += yv;
      else if ((n & 3) == 2) y2 += yv;
      else y3 += yv;
    }
    float y = (y0 + y1) + (y2 + y3);
    ygp[(size_t)tt * DI] = f2bf((y + xv * dsk) * szv);
  }
}

extern "C" void kernel_launch(void* const* d_in, const int* in_sizes, int n_in,
                              void* d_out, int out_size, void* d_ws, size_t ws_size,
                              hipStream_t stream) {
  const float* x      = (const float*)d_in[0];
  const float* W_in   = (const float*)d_in[1];
  const float* conv_w = (const float*)d_in[2];
  const float* conv_b = (const float*)d_in[3];
  const float* W_xp   = (const float*)d_in[4];
  const float* W_dt   = (const float*)d_in[5];
  const float* b_dt   = (const float*)d_in[6];
  const float* A_log  = (const float*)d_in[7];
  const float* Dskip  = (const float*)d_in[8];
  const float* W_out  = (const float*)d_in[9];
  float* out = (float*)d_out;

  char* w = (char*)d_ws;
  u16* xbf    = (u16*)w;   w += (size_t)MROWS * DM * 2;            // 8 MB
  u16* WinT   = (u16*)w;   w += (size_t)(2 * DI) * DM * 2;         // 8 MB
  u16* WoutT  = (u16*)w;   w += (size_t)DM * DI * 2;               // 4 MB
  float* xin  = (float*)w; w += (size_t)MROWS * DI * 4;            // 32 MB (aliased: dtb)
  float* sz   = (float*)w; w += (size_t)MROWS * DI * 4;            // 32 MB
  float* xc   = (float*)w; w += (size_t)MROWS * DI * 4;            // 32 MB
  float* proj = (float*)w; w += (size_t)MROWS * NPROJ * 4;         // 1.5 MB
  float* Pb   = (float*)w; w += (size_t)BATCH * NCH * NS * DI * 4; // 8 MB (aliased: yg lo)
  float* Sb   = (float*)w; w += (size_t)BATCH * NCH * NS * DI * 4; // 8 MB (aliased: yg hi)
  float* h0b  = (float*)w; w += (size_t)BATCH * NCH * NS * DI * 4; // 8 MB
  float* dtb  = xin;            // xin dead after conv_silu
  u16*   yg   = (u16*)Pb;       // P/S dead after scan2 (16 MB needed = P+S)

  cast_bf16<<<(MROWS * DM / 4 + 255) / 256, 256, 0, stream>>>(x, xbf, MROWS * DM / 4);
  transpose_cast<<<dim3((2 * DI) / 32, DM / 32), 256, 0, stream>>>(W_in, WinT, DM, 2 * DI);
  transpose_cast<<<dim3(DM / 32, DI / 32), 256, 0, stream>>>(W_out, WoutT, DI, DM);

  gemm_bt<1><<<dim3((2 * DI) / 128, MROWS / 128), 256, 0, stream>>>(
      xbf, WinT, MROWS, 2 * DI, DM, xin, sz, DI);

  conv_silu<<<(MROWS * DI / 4) / 256, 256, 0, stream>>>(xin, conv_w, conv_b, xc);

  proj_kernel<<<MROWS / 16, 256, 0, stream>>>(xc, W_xp, proj);

  dt_kernel<<<dim3(DI / 256, MROWS / 16), 256, 0, stream>>>(proj, W_dt, b_dt, dtb);

  scan1<<<dim3(NCH, DI / 256, BATCH), 256, 0, stream>>>(dtb, xc, proj, A_log, Pb, Sb);
  scan2<<<(BATCH * NS * DI) / 256, 256, 0, stream>>>(Pb, Sb, h0b);
  scan3<<<dim3(NCH, DI / 256, BATCH), 256, 0, stream>>>(dtb, xc, proj, A_log, Dskip, h0b, sz, yg);

  gemm_bt<0><<<dim3(DM / 128, MROWS / 128), 256, 0, stream>>>(
      yg, WoutT, MROWS, DM, DI, out, nullptr, 0);
}

// Round 3
// 361.454 us; speedup vs baseline: 1.5122x; 1.3719x over previous
//
#include <hip/hip_runtime.h>

#define DEV __device__ __forceinline__

typedef unsigned short u16;
typedef unsigned short u16x4 __attribute__((ext_vector_type(4)));
typedef unsigned short u16x8 __attribute__((ext_vector_type(8)));
typedef __bf16 bf16x8 __attribute__((ext_vector_type(8)));
typedef float f32x4 __attribute__((ext_vector_type(4)));
typedef float f32x2 __attribute__((ext_vector_type(2)));

#define BATCH 2
#define SEQ   2048
#define DM    1024
#define DI    2048
#define NS    16
#define RK    64
#define MROWS (BATCH * SEQ)   // 4096
#define NPROJ 96              // RK + 2*NS
#define CHUNK 64
#define NCH   (SEQ / CHUNK)   // 32

DEV u16 f2bf(float x) {
  unsigned u = __builtin_bit_cast(unsigned, x);
  u += 0x7fffu + ((u >> 16) & 1u);
  return (u16)(u >> 16);
}

// ---- MFMA dispatch: robust to either builtin signature (v8i16 or v8bf16) ----
template <typename V>
DEV auto mfma_try(V a, V b, f32x4 c, int)
    -> decltype(__builtin_amdgcn_mfma_f32_16x16x32_bf16(a, b, c, 0, 0, 0)) {
  return __builtin_amdgcn_mfma_f32_16x16x32_bf16(a, b, c, 0, 0, 0);
}
template <typename V>
DEV f32x4 mfma_try(V a, V b, f32x4 c, long) {
  return __builtin_amdgcn_mfma_f32_16x16x32_bf16(
      __builtin_bit_cast(bf16x8, a), __builtin_bit_cast(bf16x8, b), c, 0, 0, 0);
}
DEV f32x4 MFMA(u16x8 a, u16x8 b, f32x4 c) { return mfma_try(a, b, c, 0); }

// ---- async global->LDS, 16B per lane (dest = uniform base + lane*16) ----
DEV void gload16(const void* g, void* l) {
  __builtin_amdgcn_global_load_lds(
      (const __attribute__((address_space(1))) unsigned int*)g,
      (__attribute__((address_space(3))) unsigned int*)l, 16, 0, 0);
}

// Fragment-packed layout for MFMA operands:
//   P[(m>>4)*Kt + (k>>5)][lane][j], lane = ((k&15)>>2)<<4 | (m&15),
//   j = (k&3) | ((k>>4)&1)<<2   (k_local = 4*lq + (j&3) + 16*(j>>2))
// One 16-row x 32-k block = 64 lanes x 16 B = 1024 B, staged linearly.

// ---- pack x (f32 [MROWS][DM]) -> fragment-packed bf16 ----
__global__ __launch_bounds__(256)
void pack_x(const float* __restrict__ in, u16* __restrict__ out) {
  const int tid = blockIdx.x * 256 + threadIdx.x;  // fragment id
  const int lane = tid & 63, gt = tid >> 6;
  const int T = gt & 31, G = gt >> 5;              // Kt = DM/32 = 32
  const int m = (G << 4) + (lane & 15);
  const int k = (T << 5) + ((lane >> 4) << 2);
  const float* p = in + (size_t)m * DM + k;
  f32x4 lo = *(const f32x4*)p;
  f32x4 hi = *(const f32x4*)(p + 16);
  u16x8 o = { f2bf(lo[0]), f2bf(lo[1]), f2bf(lo[2]), f2bf(lo[3]),
              f2bf(hi[0]), f2bf(hi[1]), f2bf(hi[2]), f2bf(hi[3]) };
  *(u16x8*)(out + (size_t)tid * 8) = o;
}

// ---- pack weight W[K][N] (f32) -> fragment-packed bf16 of W^T (n-major) ----
__global__ __launch_bounds__(256)
void pack_w(const float* __restrict__ Wm, u16* __restrict__ out, int K, int N) {
  __shared__ float tile[32][33];
  const int n0 = blockIdx.x * 32, k0 = blockIdx.y * 32;
  const int c = threadIdx.x & 31, r = threadIdx.x >> 5;
#pragma unroll
  for (int rr = 0; rr < 32; rr += 8)
    tile[rr + r][c] = Wm[(size_t)(k0 + rr + r) * N + n0 + c];
  __syncthreads();
  const int t = threadIdx.x;
  if (t < 128) {
    const int nl = t & 31, lq = t >> 5;
    const int n = n0 + nl;
    const int Kt = K >> 5;
    u16x8 o;
#pragma unroll
    for (int j = 0; j < 4; ++j) o[j] = f2bf(tile[4 * lq + j][nl]);
#pragma unroll
    for (int j = 0; j < 4; ++j) o[4 + j] = f2bf(tile[4 * lq + 16 + j][nl]);
    size_t base = ((size_t)((n >> 4) * Kt + (k0 >> 5)) << 9)
                + (((lq << 4) | (n & 15)) << 3);
    *(u16x8*)(out + base) = o;
  }
}

// ---- bf16 MFMA GEMM on fragment-packed operands ----
// C[M,N] = A[M,K] @ BT[N,K]^T ; 128x128 tile, BK=32, 4 waves.
// EPI 0: plain f32 store to O0[M,N]
// EPI 1: col < halfN -> O0[m, col]; else O1[m, col-halfN] = silu(v)
template <int EPI>
__global__ __launch_bounds__(256)
void gemm_bt(const u16* __restrict__ A, const u16* __restrict__ BT,
             int M, int N, int K,
             float* __restrict__ O0, float* __restrict__ O1, int halfN) {
  __shared__ u16 As[4096];   // 8 groups * 512 u16 = 8 KB
  __shared__ u16 Bs[4096];
  const int t = threadIdx.x;
  const int m0 = blockIdx.y * 128, n0 = blockIdx.x * 128;
  const int lane = t & 63, wid = t >> 6;
  const int wm = (wid >> 1) * 64, wn = (wid & 1) * 64;
  const int lr = lane & 15, lq = lane >> 4;
  const int Kt = K >> 5;
  const int ga = m0 >> 4, gb = n0 >> 4;
  const int s0 = wid * 2, s1 = s0 + 1;

  f32x4 acc[4][4];
#pragma unroll
  for (int i = 0; i < 4; ++i)
#pragma unroll
    for (int j = 0; j < 4; ++j) acc[i][j] = f32x4{0.f, 0.f, 0.f, 0.f};

  for (int T = 0; T < Kt; ++T) {
    gload16(A + (((size_t)(ga + s0) * Kt + T) << 9) + lane * 8, (char*)As + s0 * 1024);
    gload16(A + (((size_t)(ga + s1) * Kt + T) << 9) + lane * 8, (char*)As + s1 * 1024);
    gload16(BT + (((size_t)(gb + s0) * Kt + T) << 9) + lane * 8, (char*)Bs + s0 * 1024);
    gload16(BT + (((size_t)(gb + s1) * Kt + T) << 9) + lane * 8, (char*)Bs + s1 * 1024);
    __syncthreads();  // vmcnt(0) drain: staged data visible

    u16x8 af[4], bfr[4];
#pragma unroll
    for (int i = 0; i < 4; ++i) {
      af[i]  = *(const u16x8*)&As[(((wm >> 4) + i) << 9) + lane * 8];
      bfr[i] = *(const u16x8*)&Bs[(((wn >> 4) + i) << 9) + lane * 8];
    }
#pragma unroll
    for (int i = 0; i < 4; ++i)
#pragma unroll
      for (int j = 0; j < 4; ++j)
        acc[i][j] = MFMA(af[i], bfr[j], acc[i][j]);
    __syncthreads();  // reads done before next stage overwrites
  }

#pragma unroll
  for (int i = 0; i < 4; ++i) {
    const int row0 = m0 + wm + i * 16 + lq * 4;
#pragma unroll
    for (int j = 0; j < 4; ++j) {
      const int col = n0 + wn + j * 16 + lr;
#pragma unroll
      for (int r = 0; r < 4; ++r) {
        float v = acc[i][j][r];
        const int row = row0 + r;
        if (EPI == 0) {
          O0[(size_t)row * N + col] = v;
        } else {
          if (col < halfN) {
            O0[(size_t)row * halfN + col] = v;
          } else {
            O1[(size_t)row * halfN + (col - halfN)] = v / (1.f + __expf(-v));
          }
        }
      }
    }
  }
}

// ---- depthwise causal conv (k=4) + SiLU ----
__global__ __launch_bounds__(256)
void conv_silu(const float* __restrict__ xin, const float* __restrict__ w,
               const float* __restrict__ cb, float* __restrict__ xc) {
  int idx = blockIdx.x * 256 + threadIdx.x;  // (b, t, d4)
  int d4 = idx & 511;
  int tt = (idx >> 9) & 2047;
  int b = idx >> 20;
  const f32x4* w4 = (const f32x4*)w;
  f32x4 wt[4];
#pragma unroll
  for (int j = 0; j < 4; ++j) wt[j] = w4[d4 * 4 + j];  // taps for d = 4*d4+j
  f32x4 acc = *(const f32x4*)(cb + d4 * 4);
#pragma unroll
  for (int k = 0; k < 4; ++k) {
    int ts = tt - 3 + k;
    if (ts >= 0) {
      f32x4 xv = *(const f32x4*)(xin + ((size_t)(b * 2048 + ts) * 512 + d4) * 4);
      acc[0] += xv[0] * wt[0][k];
      acc[1] += xv[1] * wt[1][k];
      acc[2] += xv[2] * wt[2][k];
      acc[3] += xv[3] * wt[3][k];
    }
  }
  f32x4 o;
#pragma unroll
  for (int j = 0; j < 4; ++j) o[j] = acc[j] / (1.f + __expf(-acc[j]));
  *(f32x4*)(xc + ((size_t)(b * 2048 + tt) * 512 + d4) * 4) = o;
}

// ---- proj = xc @ W_xproj : (4096,2048) @ (2048,96), fp32 ----
__global__ __launch_bounds__(256)
void proj_kernel(const float* __restrict__ xc, const float* __restrict__ Wxp,
                 float* __restrict__ proj) {
  __shared__ float xs[16][68];
  __shared__ float ws[64][96];
  const int m0 = blockIdx.x * 16;
  const int t = threadIdx.x;
  const int ml = t >> 4, ng = t & 15, nb = ng * 6;
  float acc[6] = {0.f, 0.f, 0.f, 0.f, 0.f, 0.f};
  for (int kt = 0; kt < DI; kt += 64) {
    __syncthreads();
    {
      int r = t >> 4, c4 = (t & 15) * 4;
      *(f32x4*)&xs[r][c4] = *(const f32x4*)(xc + (size_t)(m0 + r) * DI + kt + c4);
    }
#pragma unroll
    for (int q = 0; q < 6; ++q) {
      int u = t + q * 256;
      int r = u / 24, c4 = (u % 24) * 4;
      *(f32x4*)&ws[r][c4] = *(const f32x4*)(Wxp + (size_t)(kt + r) * NPROJ + c4);
    }
    __syncthreads();
#pragma unroll 4
    for (int kk = 0; kk < 64; ++kk) {
      float a = xs[ml][kk];
      f32x2 w01 = *(const f32x2*)&ws[kk][nb];
      f32x2 w23 = *(const f32x2*)&ws[kk][nb + 2];
      f32x2 w45 = *(const f32x2*)&ws[kk][nb + 4];
      acc[0] += a * w01[0]; acc[1] += a * w01[1];
      acc[2] += a * w23[0]; acc[3] += a * w23[1];
      acc[4] += a * w45[0]; acc[5] += a * w45[1];
    }
  }
#pragma unroll
  for (int j = 0; j < 6; ++j)
    proj[(size_t)(m0 + ml) * NPROJ + nb + j] = acc[j];
}

// ---- dt = softplus(proj[:, :64] @ W_dt + b_dt) : K=64 ----
__global__ __launch_bounds__(256)
void dt_kernel(const float* __restrict__ proj, const float* __restrict__ Wdt,
               const float* __restrict__ bdt, float* __restrict__ dtout) {
  __shared__ float ps[16][64];
  const int m0 = blockIdx.y * 16, nb = blockIdx.x * 256;
  const int t = threadIdx.x;
  {
    int r = t >> 4, c4 = (t & 15) * 4;
    *(f32x4*)&ps[r][c4] = *(const f32x4*)(proj + (size_t)(m0 + r) * NPROJ + c4);
  }
  __syncthreads();
  const int n = nb + t;
  float acc[16];
#pragma unroll
  for (int m = 0; m < 16; ++m) acc[m] = 0.f;
  for (int kk = 0; kk < RK; ++kk) {
    float wv = Wdt[(size_t)kk * DI + n];
#pragma unroll
    for (int m = 0; m < 16; ++m) acc[m] += ps[m][kk] * wv;
  }
  float bv = bdt[n];
#pragma unroll
  for (int m = 0; m < 16; ++m) {
    float v = acc[m] + bv;
    v = (v > 20.f) ? v : log1pf(__expf(v));
    dtout[(size_t)(m0 + m) * DI + n] = v;
  }
}

// ---- scan pass 1: thread owns d, 16 states in regs. P via exp(a*sum(dt)). ----
__global__ __launch_bounds__(256)
void scan1(const float* __restrict__ dt, const float* __restrict__ xc,
           const float* __restrict__ proj, const float* __restrict__ A_log,
           float* __restrict__ P, float* __restrict__ S) {
  __shared__ float Bs[CHUNK][16];
  const int c = blockIdx.x, dblk = blockIdx.y, b = blockIdx.z;
  const int d = (dblk << 8) + threadIdx.x;
  const size_t mbase = (size_t)b * SEQ + (size_t)c * CHUNK;
  {
    int tt = threadIdx.x >> 2, q = (threadIdx.x & 3) * 4;
    *(f32x4*)&Bs[tt][q] = *(const f32x4*)(proj + (mbase + tt) * NPROJ + RK + q);
  }
  __syncthreads();

  float a[16], h[16];
#pragma unroll
  for (int i = 0; i < 4; ++i) {
    f32x4 v = *(const f32x4*)(A_log + (size_t)d * NS + i * 4);
    a[4 * i + 0] = -__expf(v[0]); a[4 * i + 1] = -__expf(v[1]);
    a[4 * i + 2] = -__expf(v[2]); a[4 * i + 3] = -__expf(v[3]);
  }
#pragma unroll
  for (int n = 0; n < 16; ++n) h[n] = 0.f;

  float sumdt = 0.f;
  const float* dtp = dt + mbase * DI + d;
  const float* xcp = xc + mbase * DI + d;
  for (int tt = 0; tt < CHUNK; ++tt) {
    float dtv = dtp[(size_t)tt * DI];
    float xv  = xcp[(size_t)tt * DI];
    sumdt += dtv;
    float dx = dtv * xv;
    float Bv[16];
    *(f32x4*)&Bv[0]  = *(const f32x4*)&Bs[tt][0];
    *(f32x4*)&Bv[4]  = *(const f32x4*)&Bs[tt][4];
    *(f32x4*)&Bv[8]  = *(const f32x4*)&Bs[tt][8];
    *(f32x4*)&Bv[12] = *(const f32x4*)&Bs[tt][12];
#pragma unroll
    for (int n = 0; n < 16; ++n)
      h[n] = h[n] * __expf(dtv * a[n]) + dx * Bv[n];
  }

  const size_t off = ((size_t)(b * NCH + c) * NS) * DI + d;
#pragma unroll
  for (int n = 0; n < 16; ++n) {
    P[off + (size_t)n * DI] = __expf(a[n] * sumdt);
    S[off + (size_t)n * DI] = h[n];
  }
}

// ---- scan pass 2: exclusive scan across chunks ----
__global__ __launch_bounds__(256)
void scan2(const float* __restrict__ P, const float* __restrict__ S,
           float* __restrict__ h0) {
  int idx = blockIdx.x * 256 + threadIdx.x;  // [0, BATCH*NS*DI)
  int b = idx >> 15, rem = idx & 32767;
  float h = 0.f;
#pragma unroll
  for (int c = 0; c < NCH; ++c) {
    size_t off = ((size_t)(b * NCH + c) << 15) + rem;
    h0[off] = h;
    h = P[off] * h + S[off];
  }
}

// ---- scan pass 3: recompute with h0; in-register n-reduction; gate+bf16;
//      writes yg in fragment-packed layout for gemm0 (K=DI, Kt=64) ----
__global__ __launch_bounds__(256)
void scan3(const float* __restrict__ dt, const float* __restrict__ xc,
           const float* __restrict__ proj, const float* __restrict__ A_log,
           const float* __restrict__ Dskip, const float* __restrict__ h0,
           const float* __restrict__ sz, u16* __restrict__ yg) {
  __shared__ float Bs[CHUNK][16];
  __shared__ float Cs[CHUNK][16];
  const int c = blockIdx.x, dblk = blockIdx.y, b = blockIdx.z;
  const int d = (dblk << 8) + threadIdx.x;
  const size_t mbase = (size_t)b * SEQ + (size_t)c * CHUNK;
  {
    int tt = threadIdx.x >> 2, q = (threadIdx.x & 3) * 4;
    const float* pr = proj + (mbase + tt) * NPROJ + RK;
    *(f32x4*)&Bs[tt][q] = *(const f32x4*)(pr + q);
    *(f32x4*)&Cs[tt][q] = *(const f32x4*)(pr + NS + q);
  }
  __syncthreads();

  float a[16], h[16];
#pragma unroll
  for (int i = 0; i < 4; ++i) {
    f32x4 v = *(const f32x4*)(A_log + (size_t)d * NS + i * 4);
    a[4 * i + 0] = -__expf(v[0]); a[4 * i + 1] = -__expf(v[1]);
    a[4 * i + 2] = -__expf(v[2]); a[4 * i + 3] = -__expf(v[3]);
  }
  const size_t hoff = ((size_t)(b * NCH + c) * NS) * DI + d;
#pragma unroll
  for (int n = 0; n < 16; ++n) h[n] = h0[hoff + (size_t)n * DI];

  const float dsk = Dskip[d];
  const float* dtp = dt + mbase * DI + d;
  const float* xcp = xc + mbase * DI + d;
  const float* szp = sz + mbase * DI + d;

  // packed write base for this d (k-index of gemm0's A)
  const size_t dbase = ((size_t)(d >> 5) << 9) + (((d & 15) >> 2) << 7)
                     + ((d & 3) | (((d >> 4) & 1) << 2));
  const size_t mb4 = ((size_t)(mbase >> 4) << 15);

  for (int tt = 0; tt < CHUNK; ++tt) {
    float dtv = dtp[(size_t)tt * DI];
    float xv  = xcp[(size_t)tt * DI];
    float szv = szp[(size_t)tt * DI];
    float dx = dtv * xv;
    float Bv[16], Cv[16];
    *(f32x4*)&Bv[0]  = *(const f32x4*)&Bs[tt][0];
    *(f32x4*)&Bv[4]  = *(const f32x4*)&Bs[tt][4];
    *(f32x4*)&Bv[8]  = *(const f32x4*)&Bs[tt][8];
    *(f32x4*)&Bv[12] = *(const f32x4*)&Bs[tt][12];
    *(f32x4*)&Cv[0]  = *(const f32x4*)&Cs[tt][0];
    *(f32x4*)&Cv[4]  = *(const f32x4*)&Cs[tt][4];
    *(f32x4*)&Cv[8]  = *(const f32x4*)&Cs[tt][8];
    *(f32x4*)&Cv[12] = *(const f32x4*)&Cs[tt][12];
    float y0 = 0.f, y1 = 0.f, y2 = 0.f, y3 = 0.f;
#pragma unroll
    for (int n = 0; n < 16; ++n) {
      h[n] = h[n] * __expf(dtv * a[n]) + dx * Bv[n];
      float yv = h[n] * Cv[n];
      if ((n & 3) == 0) y0 += yv;
      else if ((n & 3) == 1) y1 += yv;
      else if ((n & 3) == 2) y2 += yv;
      else y3 += yv;
    }
    float y = (y0 + y1) + (y2 + y3);
    size_t addr = mb4 + ((size_t)(tt >> 4) << 15) + ((size_t)(tt & 15) << 3) + dbase;
    yg[addr] = f2bf((y + xv * dsk) * szv);
  }
}

extern "C" void kernel_launch(void* const* d_in, const int* in_sizes, int n_in,
                              void* d_out, int out_size, void* d_ws, size_t ws_size,
                              hipStream_t stream) {
  const float* x      = (const float*)d_in[0];
  const float* W_in   = (const float*)d_in[1];
  const float* conv_w = (const float*)d_in[2];
  const float* conv_b = (const float*)d_in[3];
  const float* W_xp   = (const float*)d_in[4];
  const float* W_dt   = (const float*)d_in[5];
  const float* b_dt   = (const float*)d_in[6];
  const float* A_log  = (const float*)d_in[7];
  const float* Dskip  = (const float*)d_in[8];
  const float* W_out  = (const float*)d_in[9];
  float* out = (float*)d_out;

  char* w = (char*)d_ws;
  u16* xbf    = (u16*)w;   w += (size_t)MROWS * DM * 2;            // 8 MB (packed)
  u16* WinT   = (u16*)w;   w += (size_t)(2 * DI) * DM * 2;         // 8 MB (packed)
  u16* WoutT  = (u16*)w;   w += (size_t)DM * DI * 2;               // 4 MB (packed)
  float* xin  = (float*)w; w += (size_t)MROWS * DI * 4;            // 32 MB (aliased: dtb)
  float* sz   = (float*)w; w += (size_t)MROWS * DI * 4;            // 32 MB
  float* xc   = (float*)w; w += (size_t)MROWS * DI * 4;            // 32 MB
  float* proj = (float*)w; w += (size_t)MROWS * NPROJ * 4;         // 1.5 MB
  float* Pb   = (float*)w; w += (size_t)BATCH * NCH * NS * DI * 4; // 8 MB (aliased: yg lo)
  float* Sb   = (float*)w; w += (size_t)BATCH * NCH * NS * DI * 4; // 8 MB (aliased: yg hi)
  float* h0b  = (float*)w; w += (size_t)BATCH * NCH * NS * DI * 4; // 8 MB
  float* dtb  = xin;            // xin dead after conv_silu
  u16*   yg   = (u16*)Pb;       // P/S dead after scan2 (16 MB needed = P+S)

  pack_x<<<(MROWS * DM / 8) / 256, 256, 0, stream>>>(x, xbf);
  pack_w<<<dim3((2 * DI) / 32, DM / 32), 256, 0, stream>>>(W_in, WinT, DM, 2 * DI);
  pack_w<<<dim3(DM / 32, DI / 32), 256, 0, stream>>>(W_out, WoutT, DI, DM);

  gemm_bt<1><<<dim3((2 * DI) / 128, MROWS / 128), 256, 0, stream>>>(
      xbf, WinT, MROWS, 2 * DI, DM, xin, sz, DI);

  conv_silu<<<(MROWS * DI / 4) / 256, 256, 0, stream>>>(xin, conv_w, conv_b, xc);

  proj_kernel<<<MROWS / 16, 256, 0, stream>>>(xc, W_xp, proj);

  dt_kernel<<<dim3(DI / 256, MROWS / 16), 256, 0, stream>>>(proj, W_dt, b_dt, dtb);

  scan1<<<dim3(NCH, DI / 256, BATCH), 256, 0, stream>>>(dtb, xc, proj, A_log, Pb, Sb);
  scan2<<<(BATCH * NS * DI) / 256, 256, 0, stream>>>(Pb, Sb, h0b);
  scan3<<<dim3(NCH, DI / 256, BATCH), 256, 0, stream>>>(dtb, xc, proj, A_log, Dskip, h0b, sz, yg);

  gemm_bt<0><<<dim3(DM / 128, MROWS / 128), 256, 0, stream>>>(
      yg, WoutT, MROWS, DM, DI, out, nullptr, 0);
}

// Round 4
// 315.966 us; speedup vs baseline: 1.7299x; 1.1440x over previous
//
#include <hip/hip_runtime.h>

#define DEV __device__ __forceinline__

typedef unsigned short u16;
typedef unsigned short u16x4 __attribute__((ext_vector_type(4)));
typedef unsigned short u16x8 __attribute__((ext_vector_type(8)));
typedef __bf16 bf16x8 __attribute__((ext_vector_type(8)));
typedef float f32x4 __attribute__((ext_vector_type(4)));
typedef float f32x2 __attribute__((ext_vector_type(2)));

#define BATCH 2
#define SEQ   2048
#define DM    1024
#define DI    2048
#define NS    16
#define RK    64
#define MROWS (BATCH * SEQ)   // 4096
#define NPROJ 96              // RK + 2*NS
#define CHUNK 64
#define NCH   (SEQ / CHUNK)   // 32
#define KSLC  8               // proj split-K slices
#define KSZ   (DI / KSLC)     // 256

DEV u16 f2bf(float x) {
  unsigned u = __builtin_bit_cast(unsigned, x);
  u += 0x7fffu + ((u >> 16) & 1u);
  return (u16)(u >> 16);
}

// ---- MFMA dispatch: robust to either builtin signature (v8i16 or v8bf16) ----
template <typename V>
DEV auto mfma_try(V a, V b, f32x4 c, int)
    -> decltype(__builtin_amdgcn_mfma_f32_16x16x32_bf16(a, b, c, 0, 0, 0)) {
  return __builtin_amdgcn_mfma_f32_16x16x32_bf16(a, b, c, 0, 0, 0);
}
template <typename V>
DEV f32x4 mfma_try(V a, V b, f32x4 c, long) {
  return __builtin_amdgcn_mfma_f32_16x16x32_bf16(
      __builtin_bit_cast(bf16x8, a), __builtin_bit_cast(bf16x8, b), c, 0, 0, 0);
}
DEV f32x4 MFMA(u16x8 a, u16x8 b, f32x4 c) { return mfma_try(a, b, c, 0); }

// ---- async global->LDS, 16B per lane (dest = uniform base + lane*16) ----
DEV void gload16(const void* g, void* l) {
  __builtin_amdgcn_global_load_lds(
      (const __attribute__((address_space(1))) unsigned int*)g,
      (__attribute__((address_space(3))) unsigned int*)l, 16, 0, 0);
}

// Fragment-packed layout for MFMA operands:
//   P[(m>>4)*Kt + (k>>5)][lane][j], lane = ((k&15)>>2)<<4 | (m&15),
//   j = (k&3) | ((k>>4)&1)<<2   (k_local = 4*lq + (j&3) + 16*(j>>2))
// One 16-row x 32-k block = 64 lanes x 16 B = 1024 B, staged linearly.

// ---- pack x (f32 [MROWS][DM]) -> fragment-packed bf16 ----
__global__ __launch_bounds__(256)
void pack_x(const float* __restrict__ in, u16* __restrict__ out) {
  const int tid = blockIdx.x * 256 + threadIdx.x;  // fragment id
  const int lane = tid & 63, gt = tid >> 6;
  const int T = gt & 31, G = gt >> 5;              // Kt = DM/32 = 32
  const int m = (G << 4) + (lane & 15);
  const int k = (T << 5) + ((lane >> 4) << 2);
  const float* p = in + (size_t)m * DM + k;
  f32x4 lo = *(const f32x4*)p;
  f32x4 hi = *(const f32x4*)(p + 16);
  u16x8 o = { f2bf(lo[0]), f2bf(lo[1]), f2bf(lo[2]), f2bf(lo[3]),
              f2bf(hi[0]), f2bf(hi[1]), f2bf(hi[2]), f2bf(hi[3]) };
  *(u16x8*)(out + (size_t)tid * 8) = o;
}

// ---- pack weight W[K][N] (f32) -> fragment-packed bf16 of W^T (n-major) ----
__global__ __launch_bounds__(256)
void pack_w(const float* __restrict__ Wm, u16* __restrict__ out, int K, int N) {
  __shared__ float tile[32][33];
  const int n0 = blockIdx.x * 32, k0 = blockIdx.y * 32;
  const int c = threadIdx.x & 31, r = threadIdx.x >> 5;
#pragma unroll
  for (int rr = 0; rr < 32; rr += 8)
    tile[rr + r][c] = Wm[(size_t)(k0 + rr + r) * N + n0 + c];
  __syncthreads();
  const int t = threadIdx.x;
  if (t < 128) {
    const int nl = t & 31, lq = t >> 5;
    const int n = n0 + nl;
    const int Kt = K >> 5;
    u16x8 o;
#pragma unroll
    for (int j = 0; j < 4; ++j) o[j] = f2bf(tile[4 * lq + j][nl]);
#pragma unroll
    for (int j = 0; j < 4; ++j) o[4 + j] = f2bf(tile[4 * lq + 16 + j][nl]);
    size_t base = ((size_t)((n >> 4) * Kt + (k0 >> 5)) << 9)
                + (((lq << 4) | (n & 15)) << 3);
    *(u16x8*)(out + base) = o;
  }
}

// ---- bf16 MFMA GEMM on fragment-packed operands ----
// C[M,N] = A[M,K] @ BT[N,K]^T ; 128x128 tile, BK=32, 4 waves.
// EPI 0: plain f32 store to O0[M,N]
// EPI 1: col < halfN -> O0[m, col]; else O1[m, col-halfN] = silu(v)
template <int EPI>
__global__ __launch_bounds__(256)
void gemm_bt(const u16* __restrict__ A, const u16* __restrict__ BT,
             int M, int N, int K,
             float* __restrict__ O0, float* __restrict__ O1, int halfN) {
  __shared__ u16 As[4096];   // 8 groups * 512 u16 = 8 KB
  __shared__ u16 Bs[4096];
  const int t = threadIdx.x;
  const int m0 = blockIdx.y * 128, n0 = blockIdx.x * 128;
  const int lane = t & 63, wid = t >> 6;
  const int wm = (wid >> 1) * 64, wn = (wid & 1) * 64;
  const int lr = lane & 15, lq = lane >> 4;
  const int Kt = K >> 5;
  const int ga = m0 >> 4, gb = n0 >> 4;
  const int s0 = wid * 2, s1 = s0 + 1;

  f32x4 acc[4][4];
#pragma unroll
  for (int i = 0; i < 4; ++i)
#pragma unroll
    for (int j = 0; j < 4; ++j) acc[i][j] = f32x4{0.f, 0.f, 0.f, 0.f};

  for (int T = 0; T < Kt; ++T) {
    gload16(A + (((size_t)(ga + s0) * Kt + T) << 9) + lane * 8, (char*)As + s0 * 1024);
    gload16(A + (((size_t)(ga + s1) * Kt + T) << 9) + lane * 8, (char*)As + s1 * 1024);
    gload16(BT + (((size_t)(gb + s0) * Kt + T) << 9) + lane * 8, (char*)Bs + s0 * 1024);
    gload16(BT + (((size_t)(gb + s1) * Kt + T) << 9) + lane * 8, (char*)Bs + s1 * 1024);
    __syncthreads();  // vmcnt(0) drain: staged data visible

    u16x8 af[4], bfr[4];
#pragma unroll
    for (int i = 0; i < 4; ++i) {
      af[i]  = *(const u16x8*)&As[(((wm >> 4) + i) << 9) + lane * 8];
      bfr[i] = *(const u16x8*)&Bs[(((wn >> 4) + i) << 9) + lane * 8];
    }
#pragma unroll
    for (int i = 0; i < 4; ++i)
#pragma unroll
      for (int j = 0; j < 4; ++j)
        acc[i][j] = MFMA(af[i], bfr[j], acc[i][j]);
    __syncthreads();  // reads done before next stage overwrites
  }

#pragma unroll
  for (int i = 0; i < 4; ++i) {
    const int row0 = m0 + wm + i * 16 + lq * 4;
#pragma unroll
    for (int j = 0; j < 4; ++j) {
      const int col = n0 + wn + j * 16 + lr;
#pragma unroll
      for (int r = 0; r < 4; ++r) {
        float v = acc[i][j][r];
        const int row = row0 + r;
        if (EPI == 0) {
          O0[(size_t)row * N + col] = v;
        } else {
          if (col < halfN) {
            O0[(size_t)row * halfN + col] = v;
          } else {
            O1[(size_t)row * halfN + (col - halfN)] = v / (1.f + __expf(-v));
          }
        }
      }
    }
  }
}

// ---- depthwise causal conv (k=4) + SiLU ----
__global__ __launch_bounds__(256)
void conv_silu(const float* __restrict__ xin, const float* __restrict__ w,
               const float* __restrict__ cb, float* __restrict__ xc) {
  int idx = blockIdx.x * 256 + threadIdx.x;  // (b, t, d4)
  int d4 = idx & 511;
  int tt = (idx >> 9) & 2047;
  int b = idx >> 20;
  const f32x4* w4 = (const f32x4*)w;
  f32x4 wt[4];
#pragma unroll
  for (int j = 0; j < 4; ++j) wt[j] = w4[d4 * 4 + j];  // taps for d = 4*d4+j
  f32x4 acc = *(const f32x4*)(cb + d4 * 4);
#pragma unroll
  for (int k = 0; k < 4; ++k) {
    int ts = tt - 3 + k;
    if (ts >= 0) {
      f32x4 xv = *(const f32x4*)(xin + ((size_t)(b * 2048 + ts) * 512 + d4) * 4);
      acc[0] += xv[0] * wt[0][k];
      acc[1] += xv[1] * wt[1][k];
      acc[2] += xv[2] * wt[2][k];
      acc[3] += xv[3] * wt[3][k];
    }
  }
  f32x4 o;
#pragma unroll
  for (int j = 0; j < 4; ++j) o[j] = acc[j] / (1.f + __expf(-acc[j]));
  *(f32x4*)(xc + ((size_t)(b * 2048 + tt) * 512 + d4) * 4) = o;
}

// ---- proj split-K stage 1: part[ks][32 rows][96] over K-slice of 256 ----
__global__ __launch_bounds__(256)
void proj_part(const float* __restrict__ xc, const float* __restrict__ Wxp,
               float* __restrict__ part) {
  __shared__ float xs[32][68];
  __shared__ float ws[64][96];
  const int m0 = blockIdx.x * 32;
  const int kbase = blockIdx.y * KSZ;
  const int t = threadIdx.x;
  const int mq = t >> 4, ng = t & 15, nb = ng * 6;
  float acc0[6] = {0.f, 0.f, 0.f, 0.f, 0.f, 0.f};
  float acc1[6] = {0.f, 0.f, 0.f, 0.f, 0.f, 0.f};
  for (int kt = 0; kt < KSZ; kt += 64) {
    __syncthreads();
    {
      int r = t >> 3, c8 = (t & 7) * 8;
      const float* src = xc + (size_t)(m0 + r) * DI + kbase + kt + c8;
      *(f32x4*)&xs[r][c8]     = *(const f32x4*)src;
      *(f32x4*)&xs[r][c8 + 4] = *(const f32x4*)(src + 4);
    }
#pragma unroll
    for (int q = 0; q < 6; ++q) {
      int u = t + q * 256;
      int r = u / 24, c4 = (u % 24) * 4;
      *(f32x4*)&ws[r][c4] = *(const f32x4*)(Wxp + (size_t)(kbase + kt + r) * NPROJ + c4);
    }
    __syncthreads();
#pragma unroll 4
    for (int kk = 0; kk < 64; ++kk) {
      float a0 = xs[mq][kk];
      float a1 = xs[mq + 16][kk];
      f32x2 w01 = *(const f32x2*)&ws[kk][nb];
      f32x2 w23 = *(const f32x2*)&ws[kk][nb + 2];
      f32x2 w45 = *(const f32x2*)&ws[kk][nb + 4];
      acc0[0] += a0 * w01[0]; acc0[1] += a0 * w01[1];
      acc0[2] += a0 * w23[0]; acc0[3] += a0 * w23[1];
      acc0[4] += a0 * w45[0]; acc0[5] += a0 * w45[1];
      acc1[0] += a1 * w01[0]; acc1[1] += a1 * w01[1];
      acc1[2] += a1 * w23[0]; acc1[3] += a1 * w23[1];
      acc1[4] += a1 * w45[0]; acc1[5] += a1 * w45[1];
    }
  }
  const size_t base = ((size_t)blockIdx.y * MROWS + m0) * NPROJ;
#pragma unroll
  for (int j = 0; j < 6; ++j) {
    part[base + (size_t)mq * NPROJ + nb + j]        = acc0[j];
    part[base + (size_t)(mq + 16) * NPROJ + nb + j] = acc1[j];
  }
}

// ---- proj split-K stage 2: fixed-order reduce of KSLC partials ----
__global__ __launch_bounds__(256)
void proj_reduce(const float* __restrict__ part, float* __restrict__ proj) {
  const size_t i = (size_t)(blockIdx.x * 256 + threadIdx.x) * 4;
  f32x4 s = *(const f32x4*)(part + i);
#pragma unroll
  for (int ks = 1; ks < KSLC; ++ks)
    s += *(const f32x4*)(part + (size_t)ks * MROWS * NPROJ + i);
  *(f32x4*)(proj + i) = s;
}

// ---- dt = softplus(proj[:, :64] @ W_dt + b_dt) : K=64 ----
__global__ __launch_bounds__(256)
void dt_kernel(const float* __restrict__ proj, const float* __restrict__ Wdt,
               const float* __restrict__ bdt, float* __restrict__ dtout) {
  __shared__ float ps[16][64];
  const int m0 = blockIdx.y * 16, nb = blockIdx.x * 256;
  const int t = threadIdx.x;
  {
    int r = t >> 4, c4 = (t & 15) * 4;
    *(f32x4*)&ps[r][c4] = *(const f32x4*)(proj + (size_t)(m0 + r) * NPROJ + c4);
  }
  __syncthreads();
  const int n = nb + t;
  float acc[16];
#pragma unroll
  for (int m = 0; m < 16; ++m) acc[m] = 0.f;
  for (int kk = 0; kk < RK; ++kk) {
    float wv = Wdt[(size_t)kk * DI + n];
#pragma unroll
    for (int m = 0; m < 16; ++m) acc[m] += ps[m][kk] * wv;
  }
  float bv = bdt[n];
#pragma unroll
  for (int m = 0; m < 16; ++m) {
    float v = acc[m] + bv;
    v = (v > 20.f) ? v : log1pf(__expf(v));
    dtout[(size_t)(m0 + m) * DI + n] = v;
  }
}

// ---- scan pass 1: thread owns d, 16 states in regs. P via exp(a*sum(dt)). ----
__global__ __launch_bounds__(256)
void scan1(const float* __restrict__ dt, const float* __restrict__ xc,
           const float* __restrict__ proj, const float* __restrict__ A_log,
           float* __restrict__ P, float* __restrict__ S) {
  __shared__ float Bs[CHUNK][16];
  const int c = blockIdx.x, dblk = blockIdx.y, b = blockIdx.z;
  const int d = (dblk << 8) + threadIdx.x;
  const size_t mbase = (size_t)b * SEQ + (size_t)c * CHUNK;
  {
    int tt = threadIdx.x >> 2, q = (threadIdx.x & 3) * 4;
    *(f32x4*)&Bs[tt][q] = *(const f32x4*)(proj + (mbase + tt) * NPROJ + RK + q);
  }
  __syncthreads();

  float a[16], h[16];
#pragma unroll
  for (int i = 0; i < 4; ++i) {
    f32x4 v = *(const f32x4*)(A_log + (size_t)d * NS + i * 4);
    a[4 * i + 0] = -__expf(v[0]); a[4 * i + 1] = -__expf(v[1]);
    a[4 * i + 2] = -__expf(v[2]); a[4 * i + 3] = -__expf(v[3]);
  }
#pragma unroll
  for (int n = 0; n < 16; ++n) h[n] = 0.f;

  float sumdt = 0.f;
  const float* dtp = dt + mbase * DI + d;
  const float* xcp = xc + mbase * DI + d;
  for (int tt = 0; tt < CHUNK; ++tt) {
    float dtv = dtp[(size_t)tt * DI];
    float xv  = xcp[(size_t)tt * DI];
    sumdt += dtv;
    float dx = dtv * xv;
    float Bv[16];
    *(f32x4*)&Bv[0]  = *(const f32x4*)&Bs[tt][0];
    *(f32x4*)&Bv[4]  = *(const f32x4*)&Bs[tt][4];
    *(f32x4*)&Bv[8]  = *(const f32x4*)&Bs[tt][8];
    *(f32x4*)&Bv[12] = *(const f32x4*)&Bs[tt][12];
#pragma unroll
    for (int n = 0; n < 16; ++n)
      h[n] = h[n] * __expf(dtv * a[n]) + dx * Bv[n];
  }

  const size_t off = ((size_t)(b * NCH + c) * NS) * DI + d;
#pragma unroll
  for (int n = 0; n < 16; ++n) {
    P[off + (size_t)n * DI] = __expf(a[n] * sumdt);
    S[off + (size_t)n * DI] = h[n];
  }
}

// ---- scan pass 2: exclusive scan across chunks ----
__global__ __launch_bounds__(256)
void scan2(const float* __restrict__ P, const float* __restrict__ S,
           float* __restrict__ h0) {
  int idx = blockIdx.x * 256 + threadIdx.x;  // [0, BATCH*NS*DI)
  int b = idx >> 15, rem = idx & 32767;
  float h = 0.f;
#pragma unroll
  for (int c = 0; c < NCH; ++c) {
    size_t off = ((size_t)(b * NCH + c) << 15) + rem;
    h0[off] = h;
    h = P[off] * h + S[off];
  }
}

// ---- scan pass 3: recompute with h0; in-register n-reduction; gate+bf16;
//      writes yg in fragment-packed layout for gemm0 (K=DI, Kt=64) ----
__global__ __launch_bounds__(256)
void scan3(const float* __restrict__ dt, const float* __restrict__ xc,
           const float* __restrict__ proj, const float* __restrict__ A_log,
           const float* __restrict__ Dskip, const float* __restrict__ h0,
           const float* __restrict__ sz, u16* __restrict__ yg) {
  __shared__ float Bs[CHUNK][16];
  __shared__ float Cs[CHUNK][16];
  const int c = blockIdx.x, dblk = blockIdx.y, b = blockIdx.z;
  const int d = (dblk << 8) + threadIdx.x;
  const size_t mbase = (size_t)b * SEQ + (size_t)c * CHUNK;
  {
    int tt = threadIdx.x >> 2, q = (threadIdx.x & 3) * 4;
    const float* pr = proj + (mbase + tt) * NPROJ + RK;
    *(f32x4*)&Bs[tt][q] = *(const f32x4*)(pr + q);
    *(f32x4*)&Cs[tt][q] = *(const f32x4*)(pr + NS + q);
  }
  __syncthreads();

  float a[16], h[16];
#pragma unroll
  for (int i = 0; i < 4; ++i) {
    f32x4 v = *(const f32x4*)(A_log + (size_t)d * NS + i * 4);
    a[4 * i + 0] = -__expf(v[0]); a[4 * i + 1] = -__expf(v[1]);
    a[4 * i + 2] = -__expf(v[2]); a[4 * i + 3] = -__expf(v[3]);
  }
  const size_t hoff = ((size_t)(b * NCH + c) * NS) * DI + d;
#pragma unroll
  for (int n = 0; n < 16; ++n) h[n] = h0[hoff + (size_t)n * DI];

  const float dsk = Dskip[d];
  const float* dtp = dt + mbase * DI + d;
  const float* xcp = xc + mbase * DI + d;
  const float* szp = sz + mbase * DI + d;

  // packed write base for this d (k-index of gemm0's A)
  const size_t dbase = ((size_t)(d >> 5) << 9) + (((d & 15) >> 2) << 7)
                     + ((d & 3) | (((d >> 4) & 1) << 2));
  const size_t mb4 = ((size_t)(mbase >> 4) << 15);

  for (int tt = 0; tt < CHUNK; ++tt) {
    float dtv = dtp[(size_t)tt * DI];
    float xv  = xcp[(size_t)tt * DI];
    float szv = szp[(size_t)tt * DI];
    float dx = dtv * xv;
    float Bv[16], Cv[16];
    *(f32x4*)&Bv[0]  = *(const f32x4*)&Bs[tt][0];
    *(f32x4*)&Bv[4]  = *(const f32x4*)&Bs[tt][4];
    *(f32x4*)&Bv[8]  = *(const f32x4*)&Bs[tt][8];
    *(f32x4*)&Bv[12] = *(const f32x4*)&Bs[tt][12];
    *(f32x4*)&Cv[0]  = *(const f32x4*)&Cs[tt][0];
    *(f32x4*)&Cv[4]  = *(const f32x4*)&Cs[tt][4];
    *(f32x4*)&Cv[8]  = *(const f32x4*)&Cs[tt][8];
    *(f32x4*)&Cv[12] = *(const f32x4*)&Cs[tt][12];
    float y0 = 0.f, y1 = 0.f, y2 = 0.f, y3 = 0.f;
#pragma unroll
    for (int n = 0; n < 16; ++n) {
      h[n] = h[n] * __expf(dtv * a[n]) + dx * Bv[n];
      float yv = h[n] * Cv[n];
      if ((n & 3) == 0) y0 += yv;
      else if ((n & 3) == 1) y1 += yv;
      else if ((n & 3) == 2) y2 += yv;
      else y3 += yv;
    }
    float y = (y0 + y1) + (y2 + y3);
    size_t addr = mb4 + ((size_t)(tt >> 4) << 15) + ((size_t)(tt & 15) << 3) + dbase;
    yg[addr] = f2bf((y + xv * dsk) * szv);
  }
}

extern "C" void kernel_launch(void* const* d_in, const int* in_sizes, int n_in,
                              void* d_out, int out_size, void* d_ws, size_t ws_size,
                              hipStream_t stream) {
  const float* x      = (const float*)d_in[0];
  const float* W_in   = (const float*)d_in[1];
  const float* conv_w = (const float*)d_in[2];
  const float* conv_b = (const float*)d_in[3];
  const float* W_xp   = (const float*)d_in[4];
  const float* W_dt   = (const float*)d_in[5];
  const float* b_dt   = (const float*)d_in[6];
  const float* A_log  = (const float*)d_in[7];
  const float* Dskip  = (const float*)d_in[8];
  const float* W_out  = (const float*)d_in[9];
  float* out = (float*)d_out;

  char* w = (char*)d_ws;
  u16* xbf    = (u16*)w;   w += (size_t)MROWS * DM * 2;            // 8 MB (packed)
  u16* WinT   = (u16*)w;   w += (size_t)(2 * DI) * DM * 2;         // 8 MB (packed)
  u16* WoutT  = (u16*)w;   w += (size_t)DM * DI * 2;               // 4 MB (packed)
  float* xin  = (float*)w; w += (size_t)MROWS * DI * 4;            // 32 MB (aliased: dtb)
  float* sz   = (float*)w; w += (size_t)MROWS * DI * 4;            // 32 MB
  float* xc   = (float*)w; w += (size_t)MROWS * DI * 4;            // 32 MB
  float* proj = (float*)w; w += (size_t)MROWS * NPROJ * 4;         // 1.5 MB
  float* Pb   = (float*)w; w += (size_t)BATCH * NCH * NS * DI * 4; // 8 MB (aliased: yg lo, projpart lo)
  float* Sb   = (float*)w; w += (size_t)BATCH * NCH * NS * DI * 4; // 8 MB (aliased: yg hi, projpart hi)
  float* h0b  = (float*)w; w += (size_t)BATCH * NCH * NS * DI * 4; // 8 MB
  float* dtb  = xin;            // xin dead after conv_silu
  u16*   yg   = (u16*)Pb;       // P/S dead after scan2 (16 MB needed = P+S)
  float* ppart = Pb;            // proj partials (12.6 MB) dead before scan1

  pack_x<<<(MROWS * DM / 8) / 256, 256, 0, stream>>>(x, xbf);
  pack_w<<<dim3((2 * DI) / 32, DM / 32), 256, 0, stream>>>(W_in, WinT, DM, 2 * DI);
  pack_w<<<dim3(DM / 32, DI / 32), 256, 0, stream>>>(W_out, WoutT, DI, DM);

  gemm_bt<1><<<dim3((2 * DI) / 128, MROWS / 128), 256, 0, stream>>>(
      xbf, WinT, MROWS, 2 * DI, DM, xin, sz, DI);

  conv_silu<<<(MROWS * DI / 4) / 256, 256, 0, stream>>>(xin, conv_w, conv_b, xc);

  proj_part<<<dim3(MROWS / 32, KSLC), 256, 0, stream>>>(xc, W_xp, ppart);
  proj_reduce<<<(MROWS * NPROJ / 4) / 256, 256, 0, stream>>>(ppart, proj);

  dt_kernel<<<dim3(DI / 256, MROWS / 16), 256, 0, stream>>>(proj, W_dt, b_dt, dtb);

  scan1<<<dim3(NCH, DI / 256, BATCH), 256, 0, stream>>>(dtb, xc, proj, A_log, Pb, Sb);
  scan2<<<(BATCH * NS * DI) / 256, 256, 0, stream>>>(Pb, Sb, h0b);
  scan3<<<dim3(NCH, DI / 256, BATCH), 256, 0, stream>>>(dtb, xc, proj, A_log, Dskip, h0b, sz, yg);

  gemm_bt<0><<<dim3(DM / 128, MROWS / 128), 256, 0, stream>>>(
      yg, WoutT, MROWS, DM, DI, out, nullptr, 0);
}